// Round 1
// baseline (156.843 us; speedup 1.0000x reference)
//
#include <hip/hip_runtime.h>
#include <hip/hip_bf16.h>

#define TT 8192
#define DD 64

typedef __attribute__((ext_vector_type(8))) short short8;
typedef __attribute__((ext_vector_type(4))) float f32x4;

// ws layout:
//   [0 .. 255]        float acc[ ]: acc[0] = sum exp(d2) (weighted), acc[1] = sum exp(sq)
//   [256 .. 33023]    float sq[8192]
//   [33024 .. +1MB]   __hip_bfloat16 xb[8192][64]

__global__ void prep_kernel(const float* __restrict__ x, float* __restrict__ sq,
                            __hip_bfloat16* __restrict__ xb, float* __restrict__ acc) {
    const int wave = threadIdx.x >> 6;
    const int lane = threadIdx.x & 63;
    const int row = blockIdx.x * 4 + wave;
    const float v = x[row * DD + lane];
    xb[row * DD + lane] = __float2bfloat16(v);
    float s = v * v;
    #pragma unroll
    for (int off = 32; off; off >>= 1) s += __shfl_down(s, off, 64);
    if (lane == 0) {
        sq[row] = s;
        atomicAdd(&acc[1], __expf(s));
    }
}

__global__ __launch_bounds__(256) void tile_kernel(const __hip_bfloat16* __restrict__ xb,
                                                   const float* __restrict__ sq,
                                                   float* __restrict__ acc) {
    const int tr = blockIdx.y;
    const int tc = blockIdx.x;
    if (tc < tr) return;                 // symmetry: upper-triangular tiles only
    const float w = (tc == tr) ? 1.0f : 2.0f;

    const int wid  = threadIdx.x >> 6;
    const int lane = threadIdx.x & 63;
    const int wr = wid >> 1, wc = wid & 1;     // 2x2 wave grid, 64x64 per wave
    const int brow = tr * 128 + wr * 64;
    const int bcol = tc * 128 + wc * 64;

    const int lrow = lane & 15;   // A/B fragment row within 16
    const int kgrp = lane >> 4;   // k-group 0..3 (8 contiguous bf16 each)

    f32x4 c[4][4];
    #pragma unroll
    for (int m = 0; m < 4; m++)
        #pragma unroll
        for (int n = 0; n < 4; n++)
            c[m][n] = (f32x4){0.f, 0.f, 0.f, 0.f};

    const short* xs = (const short*)xb;
    #pragma unroll
    for (int ks = 0; ks < 2; ks++) {          // K = 64 = 2 x 32
        const int koff = ks * 32 + kgrp * 8;
        short8 a[4], b[4];
        #pragma unroll
        for (int m = 0; m < 4; m++)
            a[m] = *(const short8*)(xs + (size_t)(brow + m * 16 + lrow) * DD + koff);
        #pragma unroll
        for (int n = 0; n < 4; n++)
            b[n] = *(const short8*)(xs + (size_t)(bcol + n * 16 + lrow) * DD + koff);
        #pragma unroll
        for (int m = 0; m < 4; m++)
            #pragma unroll
            for (int n = 0; n < 4; n++)
                c[m][n] = __builtin_amdgcn_mfma_f32_16x16x32_bf16(a[m], b[n], c[m][n], 0, 0, 0);
    }

    // C/D layout (m89-verified): col = lane&15, row = (lane>>4)*4 + reg
    const int crow0 = (lane >> 4) * 4;
    const int ccol  = lane & 15;
    float local = 0.f;
    #pragma unroll
    for (int n = 0; n < 4; n++) {
        const float sqc = sq[bcol + n * 16 + ccol];
        #pragma unroll
        for (int m = 0; m < 4; m++) {
            #pragma unroll
            for (int r = 0; r < 4; r++) {
                const float sqr = sq[brow + m * 16 + crow0 + r];
                local += __expf(sqr + sqc - 2.0f * c[m][n][r]);
            }
        }
    }
    local *= w;

    #pragma unroll
    for (int off = 32; off; off >>= 1) local += __shfl_down(local, off, 64);
    __shared__ float red[4];
    if (lane == 0) red[wid] = local;
    __syncthreads();
    if (threadIdx.x == 0)
        atomicAdd(&acc[0], red[0] + red[1] + red[2] + red[3]);
}

__global__ void finalize_kernel(const float* __restrict__ acc, float* __restrict__ out) {
    const float t1 = acc[0] / ((float)TT * (float)TT);
    const float t3 = acc[1] / (float)TT;
    out[0] = t1 + 1.0f + t3;
}

extern "C" void kernel_launch(void* const* d_in, const int* in_sizes, int n_in,
                              void* d_out, int out_size, void* d_ws, size_t ws_size,
                              hipStream_t stream) {
    const float* x = (const float*)d_in[0];   // xs: [4, 8192, 64] f32; only batch 0 used
    float* out = (float*)d_out;
    char* ws = (char*)d_ws;

    float* acc = (float*)ws;
    float* sq  = (float*)(ws + 256);
    __hip_bfloat16* xb = (__hip_bfloat16*)(ws + 256 + TT * sizeof(float));

    hipMemsetAsync(acc, 0, 256, stream);
    prep_kernel<<<TT / 4, 256, 0, stream>>>(x, sq, xb, acc);
    tile_kernel<<<dim3(64, 64), 256, 0, stream>>>(xb, sq, acc);
    finalize_kernel<<<1, 1, 0, stream>>>(acc, out);
}

// Round 2
// 46.437 us; speedup vs baseline: 3.3775x; 3.3775x over previous
//
#include <hip/hip_runtime.h>
#include <hip/hip_bf16.h>

#define TT 8192
#define DD 64
#define NTILE 64              // 8192 / 128
#define NP1 (NTILE * NTILE)   // tile partials
#define NP3 (TT / 4)          // prep partials (4 rows per block)

typedef __attribute__((ext_vector_type(8))) short short8;
typedef __attribute__((ext_vector_type(4))) float f32x4;

// ws layout (all float/bf16, ~1.1 MB total):
//   [0]                      float sq[8192]
//   [+32768]                 __hip_bfloat16 xb[8192][64]   (1 MB)
//   [+32768+1MB]             float p1[4096]   per-tile-block partials of sum exp(d2)
//   [+32768+1MB+16384]       float p3[2048]   per-prep-block partials of sum exp(sq)

__global__ void prep_kernel(const float* __restrict__ x, float* __restrict__ sq,
                            __hip_bfloat16* __restrict__ xb, float* __restrict__ p3) {
    const int wave = threadIdx.x >> 6;
    const int lane = threadIdx.x & 63;
    const int row = blockIdx.x * 4 + wave;
    const float v = x[row * DD + lane];
    xb[row * DD + lane] = __float2bfloat16(v);
    float s = v * v;
    #pragma unroll
    for (int off = 32; off; off >>= 1) s += __shfl_down(s, off, 64);
    __shared__ float red[4];
    if (lane == 0) {
        sq[row] = s;
        red[wave] = __expf(s);
    }
    __syncthreads();
    if (threadIdx.x == 0)
        p3[blockIdx.x] = red[0] + red[1] + red[2] + red[3];
}

__global__ __launch_bounds__(256) void tile_kernel(const __hip_bfloat16* __restrict__ xb,
                                                   const float* __restrict__ sq,
                                                   float* __restrict__ p1) {
    const int tr = blockIdx.y;
    const int tc = blockIdx.x;
    if (tc < tr) {                       // symmetry: upper-triangular tiles only
        if (threadIdx.x == 0) p1[tr * NTILE + tc] = 0.0f;  // no stale poison
        return;
    }
    const float w = (tc == tr) ? 1.0f : 2.0f;

    const int wid  = threadIdx.x >> 6;
    const int lane = threadIdx.x & 63;
    const int wr = wid >> 1, wc = wid & 1;     // 2x2 wave grid, 64x64 per wave
    const int brow = tr * 128 + wr * 64;
    const int bcol = tc * 128 + wc * 64;

    const int lrow = lane & 15;   // A/B fragment row within 16
    const int kgrp = lane >> 4;   // k-group 0..3 (8 contiguous bf16 each)

    f32x4 c[4][4];
    #pragma unroll
    for (int m = 0; m < 4; m++)
        #pragma unroll
        for (int n = 0; n < 4; n++)
            c[m][n] = (f32x4){0.f, 0.f, 0.f, 0.f};

    const short* xs = (const short*)xb;
    #pragma unroll
    for (int ks = 0; ks < 2; ks++) {          // K = 64 = 2 x 32
        const int koff = ks * 32 + kgrp * 8;
        short8 a[4], b[4];
        #pragma unroll
        for (int m = 0; m < 4; m++)
            a[m] = *(const short8*)(xs + (size_t)(brow + m * 16 + lrow) * DD + koff);
        #pragma unroll
        for (int n = 0; n < 4; n++)
            b[n] = *(const short8*)(xs + (size_t)(bcol + n * 16 + lrow) * DD + koff);
        #pragma unroll
        for (int m = 0; m < 4; m++)
            #pragma unroll
            for (int n = 0; n < 4; n++)
                c[m][n] = __builtin_amdgcn_mfma_f32_16x16x32_bf16(a[m], b[n], c[m][n], 0, 0, 0);
    }

    // C/D layout: col = lane&15, row = (lane>>4)*4 + reg
    const int crow0 = (lane >> 4) * 4;
    const int ccol  = lane & 15;
    float local = 0.f;
    #pragma unroll
    for (int n = 0; n < 4; n++) {
        const float sqc = sq[bcol + n * 16 + ccol];
        #pragma unroll
        for (int m = 0; m < 4; m++) {
            #pragma unroll
            for (int r = 0; r < 4; r++) {
                const float sqr = sq[brow + m * 16 + crow0 + r];
                local += __expf(sqr + sqc - 2.0f * c[m][n][r]);
            }
        }
    }
    local *= w;

    #pragma unroll
    for (int off = 32; off; off >>= 1) local += __shfl_down(local, off, 64);
    __shared__ float red[4];
    if (lane == 0) red[wid] = local;
    __syncthreads();
    if (threadIdx.x == 0)
        p1[tr * NTILE + tc] = red[0] + red[1] + red[2] + red[3];
}

__global__ void finalize_kernel(const float* __restrict__ p1, const float* __restrict__ p3,
                                float* __restrict__ out) {
    const int lane = threadIdx.x & 63;
    const int wid  = threadIdx.x >> 6;
    float s1 = 0.f, s3 = 0.f;
    for (int i = threadIdx.x; i < NP1; i += 256) s1 += p1[i];
    for (int i = threadIdx.x; i < NP3; i += 256) s3 += p3[i];
    #pragma unroll
    for (int off = 32; off; off >>= 1) {
        s1 += __shfl_down(s1, off, 64);
        s3 += __shfl_down(s3, off, 64);
    }
    __shared__ float r1[4], r3[4];
    if (lane == 0) { r1[wid] = s1; r3[wid] = s3; }
    __syncthreads();
    if (threadIdx.x == 0) {
        const float t1 = (r1[0] + r1[1] + r1[2] + r1[3]) / ((float)TT * (float)TT);
        const float t3 = (r3[0] + r3[1] + r3[2] + r3[3]) / (float)TT;
        out[0] = t1 + 1.0f + t3;
    }
}

extern "C" void kernel_launch(void* const* d_in, const int* in_sizes, int n_in,
                              void* d_out, int out_size, void* d_ws, size_t ws_size,
                              hipStream_t stream) {
    const float* x = (const float*)d_in[0];   // xs: [4, 8192, 64] f32; only batch 0 used
    float* out = (float*)d_out;
    char* ws = (char*)d_ws;

    float* sq = (float*)ws;
    __hip_bfloat16* xb = (__hip_bfloat16*)(ws + TT * sizeof(float));
    float* p1 = (float*)(ws + TT * sizeof(float) + (size_t)TT * DD * sizeof(__hip_bfloat16));
    float* p3 = p1 + NP1;

    prep_kernel<<<TT / 4, 256, 0, stream>>>(x, sq, xb, p3);
    tile_kernel<<<dim3(NTILE, NTILE), 256, 0, stream>>>(xb, sq, p1);
    finalize_kernel<<<1, 256, 0, stream>>>(p1, p3, out);
}

// Round 3
// 45.303 us; speedup vs baseline: 3.4621x; 1.0250x over previous
//
#include <hip/hip_runtime.h>
#include <hip/hip_bf16.h>

#define TT 8192
#define DD 64
#define NTILE 64                      // 8192 / 128
#define NBLK (NTILE * (NTILE + 1) / 2)  // 2080 upper-tri tiles
#define NP3 NTILE                     // one term3 partial per diagonal block

typedef __attribute__((ext_vector_type(8))) short short8;
typedef __attribute__((ext_vector_type(4))) float f32x4;

static __device__ __forceinline__ short f2bf(float f) {
    __hip_bfloat16 h = __float2bfloat16(f);
    return __builtin_bit_cast(short, h);
}

static __device__ __forceinline__ short8 pack8(float4 u, float4 v) {
    short8 t;
    t[0] = f2bf(u.x); t[1] = f2bf(u.y); t[2] = f2bf(u.z); t[3] = f2bf(u.w);
    t[4] = f2bf(v.x); t[5] = f2bf(v.y); t[6] = f2bf(v.z); t[7] = f2bf(v.w);
    return t;
}

// ws layout: float p1[2080] (term1 partials, weighted), float p3[64] (term3 partials)

__global__ __launch_bounds__(256) void mmd_main(const float* __restrict__ x,
                                                float* __restrict__ p1,
                                                float* __restrict__ p3) {
    const int k = blockIdx.x;
    // linear index -> upper-triangular (tr, tc), tr <= tc
    int tr = (int)((129.0f - sqrtf(16641.0f - 8.0f * (float)k)) * 0.5f);
    while (tr * NTILE - tr * (tr - 1) / 2 > k) --tr;
    while ((tr + 1) * NTILE - (tr + 1) * tr / 2 <= k) ++tr;
    const int tc = tr + (k - (tr * NTILE - tr * (tr - 1) / 2));
    const float w = (tc == tr) ? 1.0f : 2.0f;

    const int wid  = threadIdx.x >> 6;
    const int lane = threadIdx.x & 63;
    const int wr = wid >> 1, wc = wid & 1;     // 2x2 wave grid, 64x64 per wave
    const int browG = tr * 128 + wr * 64;
    const int bcolG = tc * 128 + wc * 64;
    const int lrow = lane & 15;                // fragment row within 16
    const int kgrp = lane >> 4;                // k-group (8 contiguous elems)

    __shared__ float lsqa[2][64];
    __shared__ float lsqb[2][64];
    __shared__ float red[4];
    __shared__ float red3[2];

    f32x4 c[4][4];
    #pragma unroll
    for (int m = 0; m < 4; m++)
        #pragma unroll
        for (int n = 0; n < 4; n++)
            c[m][n] = (f32x4){0.f, 0.f, 0.f, 0.f};

    float sa[4] = {0.f, 0.f, 0.f, 0.f};
    float sb[4] = {0.f, 0.f, 0.f, 0.f};

    #pragma unroll
    for (int ks = 0; ks < 2; ks++) {           // K = 64 = 2 x 32
        const int koff = ks * 32 + kgrp * 8;
        short8 a[4], b[4];
        #pragma unroll
        for (int m = 0; m < 4; m++) {
            const float* p = x + (size_t)(browG + m * 16 + lrow) * DD + koff;
            float4 u = *(const float4*)p;
            float4 v = *(const float4*)(p + 4);
            a[m] = pack8(u, v);
            sa[m] += u.x*u.x + u.y*u.y + u.z*u.z + u.w*u.w
                   + v.x*v.x + v.y*v.y + v.z*v.z + v.w*v.w;
        }
        #pragma unroll
        for (int n = 0; n < 4; n++) {
            const float* p = x + (size_t)(bcolG + n * 16 + lrow) * DD + koff;
            float4 u = *(const float4*)p;
            float4 v = *(const float4*)(p + 4);
            b[n] = pack8(u, v);
            sb[n] += u.x*u.x + u.y*u.y + u.z*u.z + u.w*u.w
                   + v.x*v.x + v.y*v.y + v.z*v.z + v.w*v.w;
        }
        #pragma unroll
        for (int m = 0; m < 4; m++)
            #pragma unroll
            for (int n = 0; n < 4; n++)
                c[m][n] = __builtin_amdgcn_mfma_f32_16x16x32_bf16(a[m], b[n], c[m][n], 0, 0, 0);
    }

    // complete row norms across the 4 k-groups (lanes l, l^16, l^32, l^48)
    #pragma unroll
    for (int m = 0; m < 4; m++) {
        sa[m] += __shfl_xor(sa[m], 16, 64);
        sa[m] += __shfl_xor(sa[m], 32, 64);
        sb[m] += __shfl_xor(sb[m], 16, 64);
        sb[m] += __shfl_xor(sb[m], 32, 64);
    }
    if (kgrp == 0) {
        if (wc == 0) {
            #pragma unroll
            for (int m = 0; m < 4; m++) lsqa[wr][m * 16 + lrow] = sa[m];
        }
        if (wr == 0) {
            #pragma unroll
            for (int n = 0; n < 4; n++) lsqb[wc][n * 16 + lrow] = sb[n];
        }
    }
    __syncthreads();

    // epilogue: sum exp(sq_r + sq_c - 2*g) via exp2
    const float L2E = 1.4426950408889634f;
    const int crow0 = (lane >> 4) * 4;         // C/D layout: row=(lane>>4)*4+reg
    const int ccol  = lane & 15;               //             col=lane&15
    float sqrl[16];
    #pragma unroll
    for (int m = 0; m < 4; m++)
        #pragma unroll
        for (int r = 0; r < 4; r++)
            sqrl[m * 4 + r] = L2E * lsqa[wr][m * 16 + crow0 + r];
    float sqcl[4];
    #pragma unroll
    for (int n = 0; n < 4; n++)
        sqcl[n] = L2E * lsqb[wc][n * 16 + ccol];

    float acc4[4] = {0.f, 0.f, 0.f, 0.f};
    #pragma unroll
    for (int n = 0; n < 4; n++)
        #pragma unroll
        for (int m = 0; m < 4; m++)
            #pragma unroll
            for (int r = 0; r < 4; r++)
                acc4[r] += exp2f(fmaf(-2.0f * L2E, c[m][n][r], sqrl[m * 4 + r] + sqcl[n]));

    float local = ((acc4[0] + acc4[1]) + (acc4[2] + acc4[3])) * w;
    #pragma unroll
    for (int off = 32; off; off >>= 1) local += __shfl_down(local, off, 64);
    if (lane == 0) red[wid] = local;
    __syncthreads();
    if (threadIdx.x == 0)
        p1[k] = red[0] + red[1] + red[2] + red[3];

    // diagonal blocks own term3 for their 128 rows
    if (tr == tc) {
        float e3 = 0.f;
        if (threadIdx.x < 128) e3 = __expf(lsqa[wid][lane]);
        #pragma unroll
        for (int off = 32; off; off >>= 1) e3 += __shfl_down(e3, off, 64);
        if (lane == 0 && wid < 2) red3[wid] = e3;
        __syncthreads();
        if (threadIdx.x == 0) p3[tr] = red3[0] + red3[1];
    }
}

__global__ void finalize_kernel(const float* __restrict__ p1, const float* __restrict__ p3,
                                float* __restrict__ out) {
    const int lane = threadIdx.x & 63;
    const int wid  = threadIdx.x >> 6;
    float s1 = 0.f, s3 = 0.f;
    for (int i = threadIdx.x; i < NBLK; i += 256) s1 += p1[i];
    if (threadIdx.x < NP3) s3 = p3[threadIdx.x];
    #pragma unroll
    for (int off = 32; off; off >>= 1) {
        s1 += __shfl_down(s1, off, 64);
        s3 += __shfl_down(s3, off, 64);
    }
    __shared__ float r1[4], r3[4];
    if (lane == 0) { r1[wid] = s1; r3[wid] = s3; }
    __syncthreads();
    if (threadIdx.x == 0) {
        const float t1 = (r1[0] + r1[1] + r1[2] + r1[3]) / ((float)TT * (float)TT);
        const float t3 = (r3[0] + r3[1] + r3[2] + r3[3]) / (float)TT;
        out[0] = t1 + 1.0f + t3;
    }
}

extern "C" void kernel_launch(void* const* d_in, const int* in_sizes, int n_in,
                              void* d_out, int out_size, void* d_ws, size_t ws_size,
                              hipStream_t stream) {
    const float* x = (const float*)d_in[0];   // xs: [4, 8192, 64] f32; only batch 0 used
    float* out = (float*)d_out;
    char* ws = (char*)d_ws;

    float* p1 = (float*)ws;
    float* p3 = p1 + NBLK;

    mmd_main<<<NBLK, 256, 0, stream>>>(x, p1, p3);
    finalize_kernel<<<1, 256, 0, stream>>>(p1, p3, out);
}

// Round 4
// 35.698 us; speedup vs baseline: 4.3936x; 1.2691x over previous
//
#include <hip/hip_runtime.h>
#include <hip/hip_bf16.h>

#define TT 8192
#define DD 64
#define NTILE 64                        // 8192 / 128
#define NBLK (NTILE * (NTILE + 1) / 2)  // 2080 upper-tri tiles
#define NPREP 512                       // prep blocks (16 rows each)
#define L2E 1.4426950408889634f

typedef __attribute__((ext_vector_type(8))) short short8;
typedef __attribute__((ext_vector_type(4))) short short4v;
typedef __attribute__((ext_vector_type(4))) float f32x4;

// ws layout:
//   [0]        float sq2[8192]        (L2E * ||x_i||^2)
//   [+32KB]    __hip_bfloat16 xb[8192][64]  (1 MB)
//   [+32KB+1MB]float p1[2080]  term1 partials (weighted)
//   then       float p3[512]   term3 partials

__global__ __launch_bounds__(256) void prep_kernel(const float* __restrict__ x,
                                                   float* __restrict__ sq2,
                                                   short* __restrict__ xb,
                                                   float* __restrict__ p3) {
    const int tid = threadIdx.x;
    const int rloc = tid >> 4;          // 0..15, row within block
    const int lane16 = tid & 15;        // 16 lanes per row
    const int row = blockIdx.x * 16 + rloc;

    const float4 u = *(const float4*)(x + (size_t)row * DD + lane16 * 4);
    short4v s4;
    s4[0] = __builtin_bit_cast(short, __float2bfloat16(u.x));
    s4[1] = __builtin_bit_cast(short, __float2bfloat16(u.y));
    s4[2] = __builtin_bit_cast(short, __float2bfloat16(u.z));
    s4[3] = __builtin_bit_cast(short, __float2bfloat16(u.w));
    *(short4v*)(xb + (size_t)row * DD + lane16 * 4) = s4;

    float s = u.x*u.x + u.y*u.y + u.z*u.z + u.w*u.w;
    #pragma unroll
    for (int off = 1; off < 16; off <<= 1) s += __shfl_xor(s, off, 64);

    __shared__ float e3[16];
    if (lane16 == 0) {
        sq2[row] = L2E * s;
        e3[rloc] = __expf(s);
    }
    __syncthreads();
    if (tid == 0) {
        float t = 0.f;
        #pragma unroll
        for (int i = 0; i < 16; i++) t += e3[i];
        p3[blockIdx.x] = t;
    }
}

__global__ __launch_bounds__(256) void mmd_main(const short* __restrict__ xb,
                                                const float* __restrict__ sq2,
                                                float* __restrict__ p1) {
    const int k = blockIdx.x;
    // linear index -> upper-triangular (tr, tc), tr <= tc
    int tr = (int)((129.0f - sqrtf(16641.0f - 8.0f * (float)k)) * 0.5f);
    while (tr * NTILE - tr * (tr - 1) / 2 > k) --tr;
    while ((tr + 1) * NTILE - (tr + 1) * tr / 2 <= k) ++tr;
    const int tc = tr + (k - (tr * NTILE - tr * (tr - 1) / 2));
    const float w = (tc == tr) ? 1.0f : 2.0f;

    const int wid  = threadIdx.x >> 6;
    const int lane = threadIdx.x & 63;
    const int wr = wid >> 1, wc = wid & 1;     // 2x2 wave grid, 64x64 per wave
    const int brow = tr * 128 + wr * 64;
    const int bcol = tc * 128 + wc * 64;
    const int lrow = lane & 15;                // fragment row within 16
    const int kgrp = lane >> 4;                // k-group (8 contiguous bf16)

    // stage pre-scaled norms: ssr = L2E*sq[rows], ssc = L2E*sq[cols]
    __shared__ float ssr[128], ssc[128];
    __shared__ float red[4];
    if (threadIdx.x < 128) ssr[threadIdx.x] = sq2[tr * 128 + threadIdx.x];
    else                   ssc[threadIdx.x - 128] = sq2[tc * 128 + (threadIdx.x - 128)];
    __syncthreads();

    f32x4 c[4][4];
    #pragma unroll
    for (int m = 0; m < 4; m++)
        #pragma unroll
        for (int n = 0; n < 4; n++)
            c[m][n] = (f32x4){0.f, 0.f, 0.f, 0.f};

    #pragma unroll
    for (int ks = 0; ks < 2; ks++) {           // K = 64 = 2 x 32
        const int koff = ks * 32 + kgrp * 8;
        short8 a[4], b[4];
        #pragma unroll
        for (int m = 0; m < 4; m++)
            a[m] = *(const short8*)(xb + (size_t)(brow + m * 16 + lrow) * DD + koff);
        #pragma unroll
        for (int n = 0; n < 4; n++)
            b[n] = *(const short8*)(xb + (size_t)(bcol + n * 16 + lrow) * DD + koff);
        #pragma unroll
        for (int m = 0; m < 4; m++)
            #pragma unroll
            for (int n = 0; n < 4; n++)
                c[m][n] = __builtin_amdgcn_mfma_f32_16x16x32_bf16(a[m], b[n], c[m][n], 0, 0, 0);
    }

    // epilogue: sum exp2(L2E*sq_r + L2E*sq_c - 2*L2E*g)
    const int crow0 = (lane >> 4) * 4;         // C/D: row=(lane>>4)*4+reg, col=lane&15
    const int ccol  = lane & 15;
    float sqrl[16];
    #pragma unroll
    for (int m = 0; m < 4; m++)
        #pragma unroll
        for (int r = 0; r < 4; r++)
            sqrl[m * 4 + r] = ssr[wr * 64 + m * 16 + crow0 + r];
    float sqcl[4];
    #pragma unroll
    for (int n = 0; n < 4; n++)
        sqcl[n] = ssc[wc * 64 + n * 16 + ccol];

    float acc4[4] = {0.f, 0.f, 0.f, 0.f};
    #pragma unroll
    for (int n = 0; n < 4; n++)
        #pragma unroll
        for (int m = 0; m < 4; m++)
            #pragma unroll
            for (int r = 0; r < 4; r++)
                acc4[r] += exp2f(fmaf(-2.0f * L2E, c[m][n][r], sqrl[m * 4 + r] + sqcl[n]));

    float local = ((acc4[0] + acc4[1]) + (acc4[2] + acc4[3])) * w;
    #pragma unroll
    for (int off = 32; off; off >>= 1) local += __shfl_down(local, off, 64);
    if (lane == 0) red[wid] = local;
    __syncthreads();
    if (threadIdx.x == 0)
        p1[k] = red[0] + red[1] + red[2] + red[3];
}

__global__ void finalize_kernel(const float* __restrict__ p1, const float* __restrict__ p3,
                                float* __restrict__ out) {
    const int lane = threadIdx.x & 63;
    const int wid  = threadIdx.x >> 6;
    float s1 = 0.f, s3 = 0.f;
    for (int i = threadIdx.x; i < NBLK; i += 256) s1 += p1[i];
    for (int i = threadIdx.x; i < NPREP; i += 256) s3 += p3[i];
    #pragma unroll
    for (int off = 32; off; off >>= 1) {
        s1 += __shfl_down(s1, off, 64);
        s3 += __shfl_down(s3, off, 64);
    }
    __shared__ float r1[4], r3[4];
    if (lane == 0) { r1[wid] = s1; r3[wid] = s3; }
    __syncthreads();
    if (threadIdx.x == 0) {
        const float t1 = (r1[0] + r1[1] + r1[2] + r1[3]) / ((float)TT * (float)TT);
        const float t3 = (r3[0] + r3[1] + r3[2] + r3[3]) / (float)TT;
        out[0] = t1 + 1.0f + t3;
    }
}

extern "C" void kernel_launch(void* const* d_in, const int* in_sizes, int n_in,
                              void* d_out, int out_size, void* d_ws, size_t ws_size,
                              hipStream_t stream) {
    const float* x = (const float*)d_in[0];   // xs: [4, 8192, 64] f32; only batch 0 used
    float* out = (float*)d_out;
    char* ws = (char*)d_ws;

    float* sq2 = (float*)ws;
    short* xb = (short*)(ws + TT * sizeof(float));
    float* p1 = (float*)(ws + TT * sizeof(float) + (size_t)TT * DD * sizeof(short));
    float* p3 = p1 + NBLK;

    prep_kernel<<<NPREP, 256, 0, stream>>>(x, sq2, xb, p3);
    mmd_main<<<NBLK, 256, 0, stream>>>(xb, sq2, p1);
    finalize_kernel<<<1, 256, 0, stream>>>(p1, p3, out);
}

// Round 5
// 33.626 us; speedup vs baseline: 4.6643x; 1.0616x over previous
//
#include <hip/hip_runtime.h>
#include <hip/hip_bf16.h>

#define TT 8192
#define DD 64
#define NTILE 64                        // 8192 / 128
#define NBLK (NTILE * (NTILE + 1) / 2)  // 2080 upper-tri tiles
#define NPREP 512                       // prep blocks (16 rows each)
#define L2E 1.4426950408889634f

typedef __attribute__((ext_vector_type(8))) short short8;
typedef __attribute__((ext_vector_type(4))) short short4v;
typedef __attribute__((ext_vector_type(4))) float f32x4;

static __device__ __forceinline__ float fast_exp2(float x) {
#if __has_builtin(__builtin_amdgcn_exp2f)
    return __builtin_amdgcn_exp2f(x);   // raw v_exp_f32; args bounded, no fixup needed
#else
    float r; asm volatile("v_exp_f32 %0, %1" : "=v"(r) : "v"(x)); return r;
#endif
}

// ws layout:
//   [0]        float sq2[8192]        (L2E * ||x_i||^2)
//   [+32KB]    __hip_bfloat16 xb[8192][64]  (1 MB)
//   [+32KB+1MB]float p1[2080]  term1 partials (weighted)
//   then       float p3[512]   term3 partials

__global__ __launch_bounds__(256) void prep_kernel(const float* __restrict__ x,
                                                   float* __restrict__ sq2,
                                                   short* __restrict__ xb,
                                                   float* __restrict__ p3) {
    const int tid = threadIdx.x;
    const int rloc = tid >> 4;          // 0..15, row within block
    const int lane16 = tid & 15;        // 16 lanes per row
    const int row = blockIdx.x * 16 + rloc;

    const float4 u = *(const float4*)(x + (size_t)row * DD + lane16 * 4);
    short4v s4;
    s4[0] = __builtin_bit_cast(short, __float2bfloat16(u.x));
    s4[1] = __builtin_bit_cast(short, __float2bfloat16(u.y));
    s4[2] = __builtin_bit_cast(short, __float2bfloat16(u.z));
    s4[3] = __builtin_bit_cast(short, __float2bfloat16(u.w));
    *(short4v*)(xb + (size_t)row * DD + lane16 * 4) = s4;

    float s = u.x*u.x + u.y*u.y + u.z*u.z + u.w*u.w;
    #pragma unroll
    for (int off = 1; off < 16; off <<= 1) s += __shfl_xor(s, off, 64);

    __shared__ float e3[16];
    if (lane16 == 0) {
        sq2[row] = L2E * s;
        e3[rloc] = __expf(s);
    }
    __syncthreads();
    if (tid == 0) {
        float t = 0.f;
        #pragma unroll
        for (int i = 0; i < 16; i++) t += e3[i];
        p3[blockIdx.x] = t;
    }
}

__global__ __launch_bounds__(256) void mmd_main(const short* __restrict__ xb,
                                                const float* __restrict__ sq2,
                                                float* __restrict__ p1) {
    const int k = blockIdx.x;
    // linear index -> upper-triangular (tr, tc), tr <= tc
    int tr = (int)((129.0f - sqrtf(16641.0f - 8.0f * (float)k)) * 0.5f);
    while (tr * NTILE - tr * (tr - 1) / 2 > k) --tr;
    while ((tr + 1) * NTILE - (tr + 1) * tr / 2 <= k) ++tr;
    const int tc = tr + (k - (tr * NTILE - tr * (tr - 1) / 2));
    const float w = (tc == tr) ? 1.0f : 2.0f;

    const int wid  = threadIdx.x >> 6;
    const int lane = threadIdx.x & 63;
    const int wr = wid >> 1, wc = wid & 1;     // 2x2 wave grid, 64x64 per wave
    const int brow = tr * 128 + wr * 64;
    const int bcol = tc * 128 + wc * 64;
    const int lrow = lane & 15;                // fragment row within 16
    const int kgrp = lane >> 4;                // k-group (8 contiguous bf16)

    // stage pre-scaled norms: L2E*sq for the block's rows/cols
    __shared__ float ssr[128], ssc[128];
    __shared__ float red[4];
    if (threadIdx.x < 128) ssr[threadIdx.x] = sq2[tr * 128 + threadIdx.x];
    else                   ssc[threadIdx.x - 128] = sq2[tc * 128 + (threadIdx.x - 128)];

    // issue ALL 16 fragment loads back-to-back (ILP covers L2 latency)
    short8 a[2][4], b[2][4];
    #pragma unroll
    for (int ks = 0; ks < 2; ks++) {
        const int koff = ks * 32 + kgrp * 8;
        #pragma unroll
        for (int m = 0; m < 4; m++)
            a[ks][m] = *(const short8*)(xb + (size_t)(brow + m * 16 + lrow) * DD + koff);
        #pragma unroll
        for (int n = 0; n < 4; n++)
            b[ks][n] = *(const short8*)(xb + (size_t)(bcol + n * 16 + lrow) * DD + koff);
    }

    f32x4 c[4][4];
    #pragma unroll
    for (int m = 0; m < 4; m++)
        #pragma unroll
        for (int n = 0; n < 4; n++)
            c[m][n] = (f32x4){0.f, 0.f, 0.f, 0.f};

    #pragma unroll
    for (int ks = 0; ks < 2; ks++)
        #pragma unroll
        for (int m = 0; m < 4; m++)
            #pragma unroll
            for (int n = 0; n < 4; n++)
                c[m][n] = __builtin_amdgcn_mfma_f32_16x16x32_bf16(a[ks][m], b[ks][n], c[m][n], 0, 0, 0);

    __syncthreads();   // ssr/ssc ready (overlapped with loads+MFMA)

    // epilogue: sum exp2(L2E*sq_r + L2E*sq_c - 2*L2E*g)
    const int crow0 = (lane >> 4) * 4;         // C/D: row=(lane>>4)*4+reg, col=lane&15
    const int ccol  = lane & 15;
    float sqrl[16];
    #pragma unroll
    for (int m = 0; m < 4; m++)
        #pragma unroll
        for (int r = 0; r < 4; r++)
            sqrl[m * 4 + r] = ssr[wr * 64 + m * 16 + crow0 + r];
    float sqcl[4];
    #pragma unroll
    for (int n = 0; n < 4; n++)
        sqcl[n] = ssc[wc * 64 + n * 16 + ccol];

    float acc4[4] = {0.f, 0.f, 0.f, 0.f};
    #pragma unroll
    for (int n = 0; n < 4; n++)
        #pragma unroll
        for (int m = 0; m < 4; m++)
            #pragma unroll
            for (int r = 0; r < 4; r++)
                acc4[r] += fast_exp2(fmaf(-2.0f * L2E, c[m][n][r], sqrl[m * 4 + r] + sqcl[n]));

    float local = ((acc4[0] + acc4[1]) + (acc4[2] + acc4[3])) * w;
    #pragma unroll
    for (int off = 32; off; off >>= 1) local += __shfl_down(local, off, 64);
    if (lane == 0) red[wid] = local;
    __syncthreads();
    if (threadIdx.x == 0)
        p1[k] = red[0] + red[1] + red[2] + red[3];
}

__global__ void finalize_kernel(const float* __restrict__ p1, const float* __restrict__ p3,
                                float* __restrict__ out) {
    const int lane = threadIdx.x & 63;
    const int wid  = threadIdx.x >> 6;
    float s1 = 0.f, s3 = 0.f;
    for (int i = threadIdx.x; i < NBLK; i += 256) s1 += p1[i];
    for (int i = threadIdx.x; i < NPREP; i += 256) s3 += p3[i];
    #pragma unroll
    for (int off = 32; off; off >>= 1) {
        s1 += __shfl_down(s1, off, 64);
        s3 += __shfl_down(s3, off, 64);
    }
    __shared__ float r1[4], r3[4];
    if (lane == 0) { r1[wid] = s1; r3[wid] = s3; }
    __syncthreads();
    if (threadIdx.x == 0) {
        const float t1 = (r1[0] + r1[1] + r1[2] + r1[3]) / ((float)TT * (float)TT);
        const float t3 = (r3[0] + r3[1] + r3[2] + r3[3]) / (float)TT;
        out[0] = t1 + 1.0f + t3;
    }
}

extern "C" void kernel_launch(void* const* d_in, const int* in_sizes, int n_in,
                              void* d_out, int out_size, void* d_ws, size_t ws_size,
                              hipStream_t stream) {
    const float* x = (const float*)d_in[0];   // xs: [4, 8192, 64] f32; only batch 0 used
    float* out = (float*)d_out;
    char* ws = (char*)d_ws;

    float* sq2 = (float*)ws;
    short* xb = (short*)(ws + TT * sizeof(float));
    float* p1 = (float*)(ws + TT * sizeof(float) + (size_t)TT * DD * sizeof(short));
    float* p3 = p1 + NBLK;

    prep_kernel<<<NPREP, 256, 0, stream>>>(x, sq2, xb, p3);
    mmd_main<<<NBLK, 256, 0, stream>>>(xb, sq2, p1);
    finalize_kernel<<<1, 256, 0, stream>>>(p1, p3, out);
}